// Round 2
// baseline (533.917 us; speedup 1.0000x reference)
//
#include <hip/hip_runtime.h>

// GraphAE: 2x GCNConv encoder + 2-layer MLP decoder.
// N=50000, IN=128, HID=256, LAT=64, E=800000. All fp32.
// NOTE: harness delivers integer inputs as int32 -> edge_index is const int*.
//
// Pipeline (all on `stream`):
//   memset counts=0
//   hist(dst) -> counts
//   scan1/scan2/scan3 -> rowptr[N+1], next[i]=rowptr[i]
//   fill -> col[E]  (CSR of incoming edges per dst)
//   dinv[i] = rsqrt(counts[i]+1)          (self-loop included)
//   GEMM1: hs  = (x @ W1)   * dinv[row]
//   AGG1:  out1 = relu(dinv[i]*(hs[i] + sum_in hs[src]) + b1)
//   GEMM2: zs  = (out1 @ W2) * dinv[row]
//   AGG2:  z   = dinv[i]*(zs[i] + sum_in zs[src]) + b2
//   GEMM3: d   = relu(z @ Wd1 + bd1)      (reuses hs buffer)
//   GEMM4: out = d @ Wd2 + bd2

#define IN_CH  128
#define HIDDEN 256
#define LATENT 64

static __device__ __forceinline__ float4 ld4(const float* p) {
    return *reinterpret_cast<const float4*>(p);
}
static __device__ __forceinline__ void st4(float* p, float4 v) {
    *reinterpret_cast<float4*>(p) = v;
}

// ---------------- graph structure kernels ----------------

__global__ void hist_kernel(const int* __restrict__ ei, int E, int* __restrict__ counts) {
    int e = blockIdx.x * 256 + threadIdx.x;
    if (e < E) {
        int d = ei[E + e];  // second row = dst
        atomicAdd(&counts[d], 1);
    }
}

__global__ void scan1_kernel(const int* __restrict__ counts, int* __restrict__ rowptr,
                             int* __restrict__ blocksums, int N) {
    __shared__ int sh[256];
    int tid = threadIdx.x;
    int i = blockIdx.x * 256 + tid;
    int v = (i < N) ? counts[i] : 0;
    sh[tid] = v;
    __syncthreads();
    for (int off = 1; off < 256; off <<= 1) {
        int t = (tid >= off) ? sh[tid - off] : 0;
        __syncthreads();
        sh[tid] += t;
        __syncthreads();
    }
    if (i < N) rowptr[i] = sh[tid] - v;  // exclusive within block
    if (tid == 255) blocksums[blockIdx.x] = sh[255];
}

__global__ void scan2_kernel(const int* __restrict__ blocksums, int* __restrict__ blockoffs,
                             int* __restrict__ rowptr, int nblk, int N) {
    __shared__ int sh[256];
    int tid = threadIdx.x;
    int v = (tid < nblk) ? blocksums[tid] : 0;
    sh[tid] = v;
    __syncthreads();
    for (int off = 1; off < 256; off <<= 1) {
        int t = (tid >= off) ? sh[tid - off] : 0;
        __syncthreads();
        sh[tid] += t;
        __syncthreads();
    }
    if (tid < nblk) blockoffs[tid] = sh[tid] - v;
    if (tid == nblk - 1) rowptr[N] = sh[tid];  // total = E
}

__global__ void scan3_kernel(int* __restrict__ rowptr, const int* __restrict__ blockoffs,
                             int* __restrict__ next, int N) {
    int i = blockIdx.x * 256 + threadIdx.x;
    if (i < N) {
        int r = rowptr[i] + blockoffs[i >> 8];
        rowptr[i] = r;
        next[i] = r;
    }
}

__global__ void fill_kernel(const int* __restrict__ ei, int E,
                            int* __restrict__ next, int* __restrict__ col) {
    int e = blockIdx.x * 256 + threadIdx.x;
    if (e < E) {
        int s = ei[e];
        int d = ei[E + e];
        int pos = atomicAdd(&next[d], 1);
        col[pos] = s;
    }
}

__global__ void dinv_kernel(const int* __restrict__ counts, float* __restrict__ dinv, int N) {
    int i = blockIdx.x * 256 + threadIdx.x;
    if (i < N) dinv[i] = rsqrtf((float)counts[i] + 1.0f);
}

// ---------------- fp32 tiled GEMM ----------------
// C[M,N] = op(A[M,K] @ B[K,N]); 64x64 tile, BK=16, 256 threads, 4x4 microtile.
// SCALE_DINV: C *= dinv[row] (GCN pre-scale, no bias)
// ADD_BIAS:   C += bias[col]; RELU: max(0, .)

template <bool SCALE_DINV, bool ADD_BIAS, bool RELU>
__global__ __launch_bounds__(256) void gemm_f32(
    const float* __restrict__ A, const float* __restrict__ B, float* __restrict__ C,
    const float* __restrict__ dinv, const float* __restrict__ bias,
    int M, int K, int N) {
    const int BM = 64, BN = 64, BK = 16;
    __shared__ float As[BK][BM + 4];  // [k][m]
    __shared__ float Bs[BK][BN + 4];  // [k][n]

    const int tid = threadIdx.x;
    const int tx = tid & 15;        // col group
    const int ty = tid >> 4;        // row group
    const int row0 = blockIdx.x * BM;
    const int n0 = blockIdx.y * BN;

    // stage mapping: A: thread -> (m = tid>>2, k4 = (tid&3)*4)
    const int am = tid >> 2;
    const int ak4 = (tid & 3) * 4;
    // B: thread -> (k = tid>>4, n4 = (tid&15)*4)
    const int bk = tid >> 4;
    const int bn4 = (tid & 15) * 4;

    float acc[4][4];
#pragma unroll
    for (int i = 0; i < 4; i++)
#pragma unroll
        for (int j = 0; j < 4; j++) acc[i][j] = 0.0f;

    for (int k0 = 0; k0 < K; k0 += BK) {
        // stage A tile
        {
            int row = row0 + am;
            float4 v = make_float4(0.f, 0.f, 0.f, 0.f);
            if (row < M) v = ld4(&A[(long)row * K + k0 + ak4]);
            As[ak4 + 0][am] = v.x;
            As[ak4 + 1][am] = v.y;
            As[ak4 + 2][am] = v.z;
            As[ak4 + 3][am] = v.w;
        }
        // stage B tile (K,N always multiples of tile -> no guard)
        {
            float4 v = ld4(&B[(long)(k0 + bk) * N + n0 + bn4]);
            st4(&Bs[bk][bn4], v);
        }
        __syncthreads();
#pragma unroll
        for (int k = 0; k < BK; k++) {
            float4 a = ld4(&As[k][ty * 4]);
            float4 b = ld4(&Bs[k][tx * 4]);
            acc[0][0] += a.x * b.x; acc[0][1] += a.x * b.y; acc[0][2] += a.x * b.z; acc[0][3] += a.x * b.w;
            acc[1][0] += a.y * b.x; acc[1][1] += a.y * b.y; acc[1][2] += a.y * b.z; acc[1][3] += a.y * b.w;
            acc[2][0] += a.z * b.x; acc[2][1] += a.z * b.y; acc[2][2] += a.z * b.z; acc[2][3] += a.z * b.w;
            acc[3][0] += a.w * b.x; acc[3][1] += a.w * b.y; acc[3][2] += a.w * b.z; acc[3][3] += a.w * b.w;
        }
        __syncthreads();
    }

    const int col0 = n0 + tx * 4;
    float4 bia = make_float4(0.f, 0.f, 0.f, 0.f);
    if (ADD_BIAS) bia = ld4(&bias[col0]);
#pragma unroll
    for (int i = 0; i < 4; i++) {
        int row = row0 + ty * 4 + i;
        if (row < M) {
            float4 v = make_float4(acc[i][0], acc[i][1], acc[i][2], acc[i][3]);
            if (SCALE_DINV) {
                float s = dinv[row];
                v.x *= s; v.y *= s; v.z *= s; v.w *= s;
            }
            if (ADD_BIAS) { v.x += bia.x; v.y += bia.y; v.z += bia.z; v.w += bia.w; }
            if (RELU) {
                v.x = fmaxf(v.x, 0.f); v.y = fmaxf(v.y, 0.f);
                v.z = fmaxf(v.z, 0.f); v.w = fmaxf(v.w, 0.f);
            }
            st4(&C[(long)row * N + col0], v);
        }
    }
}

// ---------------- aggregation kernels ----------------
// AGG1: 256 channels. One wave per node; lane handles 4 channels (float4).
__global__ __launch_bounds__(256) void agg256_relu_kernel(
    const float* __restrict__ hs, const int* __restrict__ rowptr, const int* __restrict__ col,
    const float* __restrict__ dinv, const float* __restrict__ bias,
    float* __restrict__ out, int N) {
    int wave = threadIdx.x >> 6;
    int lane = threadIdx.x & 63;
    int node = blockIdx.x * 4 + wave;
    if (node >= N) return;
    int c = lane * 4;
    float4 acc = ld4(&hs[(long)node * 256 + c]);  // self-loop term
    int beg = rowptr[node];
    int end = rowptr[node + 1];
    for (int e = beg; e < end; e++) {
        int s = col[e];
        float4 v = ld4(&hs[(long)s * 256 + c]);
        acc.x += v.x; acc.y += v.y; acc.z += v.z; acc.w += v.w;
    }
    float sc = dinv[node];
    float4 b = ld4(&bias[c]);
    float4 r;
    r.x = fmaxf(acc.x * sc + b.x, 0.f);
    r.y = fmaxf(acc.y * sc + b.y, 0.f);
    r.z = fmaxf(acc.z * sc + b.z, 0.f);
    r.w = fmaxf(acc.w * sc + b.w, 0.f);
    st4(&out[(long)node * 256 + c], r);
}

// AGG2: 64 channels. One wave per node; lane = channel. No relu.
__global__ __launch_bounds__(256) void agg64_kernel(
    const float* __restrict__ zs, const int* __restrict__ rowptr, const int* __restrict__ col,
    const float* __restrict__ dinv, const float* __restrict__ bias,
    float* __restrict__ out, int N) {
    int wave = threadIdx.x >> 6;
    int lane = threadIdx.x & 63;
    int node = blockIdx.x * 4 + wave;
    if (node >= N) return;
    float acc = zs[(long)node * 64 + lane];
    int beg = rowptr[node];
    int end = rowptr[node + 1];
    for (int e = beg; e < end; e++) {
        int s = col[e];
        acc += zs[(long)s * 64 + lane];
    }
    out[(long)node * 64 + lane] = acc * dinv[node] + bias[lane];
}

// ---------------- launch ----------------

extern "C" void kernel_launch(void* const* d_in, const int* in_sizes, int n_in,
                              void* d_out, int out_size, void* d_ws, size_t ws_size,
                              hipStream_t stream) {
    const float* x        = (const float*)d_in[0];
    const int* ei         = (const int*)d_in[1];   // int32! (harness integer convention)
    const float* W1       = (const float*)d_in[2];
    const float* b1       = (const float*)d_in[3];
    const float* W2       = (const float*)d_in[4];
    const float* b2       = (const float*)d_in[5];
    const float* Wd1      = (const float*)d_in[6];
    const float* bd1      = (const float*)d_in[7];
    const float* Wd2      = (const float*)d_in[8];
    const float* bd2      = (const float*)d_in[9];
    float* out            = (float*)d_out;

    const int N = in_sizes[0] / IN_CH;   // 50000
    const int E = in_sizes[1] / 2;       // 800000

    // workspace layout (256B aligned)
    char* p = (char*)d_ws;
    auto alloc = [&](size_t bytes) {
        char* r = p;
        p += (bytes + 255) & ~(size_t)255;
        return r;
    };
    int*   counts    = (int*)  alloc((size_t)(N + 1) * 4);
    int*   rowptr    = (int*)  alloc((size_t)(N + 1) * 4);
    int*   nxt       = (int*)  alloc((size_t)N * 4);
    int*   blocksums = (int*)  alloc(256 * 4);
    int*   blockoffs = (int*)  alloc(256 * 4);
    float* dinv      = (float*)alloc((size_t)N * 4);
    int*   col       = (int*)  alloc((size_t)E * 4);
    float* hs        = (float*)alloc((size_t)N * HIDDEN * 4);  // reused as d
    float* out1      = (float*)alloc((size_t)N * HIDDEN * 4);
    float* zs        = (float*)alloc((size_t)N * LATENT * 4);
    float* z         = (float*)alloc((size_t)N * LATENT * 4);
    float* d         = hs;  // hs dead after AGG1; d written at GEMM3

    const int nblk = (N + 255) / 256;  // 196

    hipMemsetAsync(counts, 0, (size_t)(N + 1) * 4, stream);
    hist_kernel<<<(E + 255) / 256, 256, 0, stream>>>(ei, E, counts);
    scan1_kernel<<<nblk, 256, 0, stream>>>(counts, rowptr, blocksums, N);
    scan2_kernel<<<1, 256, 0, stream>>>(blocksums, blockoffs, rowptr, nblk, N);
    scan3_kernel<<<nblk, 256, 0, stream>>>(rowptr, blockoffs, nxt, N);
    fill_kernel<<<(E + 255) / 256, 256, 0, stream>>>(ei, E, nxt, col);
    dinv_kernel<<<nblk, 256, 0, stream>>>(counts, dinv, N);

    const int mblk = (N + 63) / 64;  // 782

    // GEMM1: hs = (x @ W1) * dinv[row]   [N,128]x[128,256]
    gemm_f32<true, false, false><<<dim3(mblk, HIDDEN / 64), 256, 0, stream>>>(
        x, W1, hs, dinv, nullptr, N, IN_CH, HIDDEN);
    // AGG1: out1 = relu(dinv*(sum) + b1)
    agg256_relu_kernel<<<(N + 3) / 4, 256, 0, stream>>>(hs, rowptr, col, dinv, b1, out1, N);
    // GEMM2: zs = (out1 @ W2) * dinv[row]  [N,256]x[256,64]
    gemm_f32<true, false, false><<<dim3(mblk, LATENT / 64), 256, 0, stream>>>(
        out1, W2, zs, dinv, nullptr, N, HIDDEN, LATENT);
    // AGG2: z = dinv*(sum) + b2
    agg64_kernel<<<(N + 3) / 4, 256, 0, stream>>>(zs, rowptr, col, dinv, b2, z, N);
    // GEMM3: d = relu(z @ Wd1 + bd1)   [N,64]x[64,256]
    gemm_f32<false, true, true><<<dim3(mblk, HIDDEN / 64), 256, 0, stream>>>(
        z, Wd1, d, nullptr, bd1, N, LATENT, HIDDEN);
    // GEMM4: out = d @ Wd2 + bd2      [N,256]x[256,128]
    gemm_f32<false, true, false><<<dim3(mblk, IN_CH / 64), 256, 0, stream>>>(
        d, Wd2, out, nullptr, bd2, N, HIDDEN, IN_CH);
}